// Round 1
// baseline (6945.883 us; speedup 1.0000x reference)
//
#include <hip/hip_runtime.h>
#include <cstddef>
#include <cstdint>

// ---------------------------------------------------------------------------
// Problem constants (from reference)
// ---------------------------------------------------------------------------
#define BB   8192      // batch B
#define AA   16        // agents A
#define BA   131072    // B*A rows
#define HID  256
#define NK   32
#define NQ   32
#define NV   128
#define IN_DIM  512
#define CUR_HID 512
#define CUR_OUT 128
#define N_ACT   64

// ---------------------------------------------------------------------------
// Generic f32 tiled GEMM:  C[M,N] = act( (acc ? C : 0) + A[M,K] @ W[K,N] + b )
// W row-major with leading dim ldw. M must be a multiple of 64. K a multiple
// of 32. N guarded. act: 0 = none, 1 = relu. acc: 1 = add to existing C.
// ---------------------------------------------------------------------------
#define TILE_M 64
#define TILE_N 64
#define TILE_K 32

__global__ __launch_bounds__(256)
void gemm_f32(const float* __restrict__ A, const float* __restrict__ W,
              const float* __restrict__ bias, float* __restrict__ C,
              int M, int N, int K, int ldw, int act, int acc)
{
    __shared__ float As[TILE_M][TILE_K + 1];          // +1 pad: bank-conflict-free col reads
    __shared__ __align__(16) float Ws[TILE_K][TILE_N];

    const int tid  = threadIdx.x;
    const int tx   = tid & 15;          // 0..15 -> output col group
    const int ty   = tid >> 4;          // 0..15 -> output row group
    const int brow = blockIdx.y * TILE_M;
    const int bcol = blockIdx.x * TILE_N;

    float acc4[4][4];
#pragma unroll
    for (int r = 0; r < 4; ++r)
#pragma unroll
        for (int c = 0; c < 4; ++c) acc4[r][c] = 0.f;

    for (int k0 = 0; k0 < K; k0 += TILE_K) {
        // A tile: 64x32 floats, 2048 elems, 8 per thread (coalesced per row)
#pragma unroll
        for (int i = 0; i < (TILE_M * TILE_K) / 256; ++i) {
            int e = tid + i * 256;
            int r = e >> 5;
            int c = e & 31;
            As[r][c] = A[(size_t)(brow + r) * K + (k0 + c)];
        }
        // W tile: 32x64 floats, N-guarded
#pragma unroll
        for (int i = 0; i < (TILE_K * TILE_N) / 256; ++i) {
            int e = tid + i * 256;
            int r = e >> 6;
            int c = e & 63;
            int gc = bcol + c;
            Ws[r][c] = (gc < N) ? W[(size_t)(k0 + r) * ldw + gc] : 0.f;
        }
        __syncthreads();

#pragma unroll
        for (int kk = 0; kk < TILE_K; ++kk) {
            float a0 = As[ty * 4 + 0][kk];
            float a1 = As[ty * 4 + 1][kk];
            float a2 = As[ty * 4 + 2][kk];
            float a3 = As[ty * 4 + 3][kk];
            const float4 w = *reinterpret_cast<const float4*>(&Ws[kk][tx * 4]);
            acc4[0][0] += a0 * w.x; acc4[0][1] += a0 * w.y; acc4[0][2] += a0 * w.z; acc4[0][3] += a0 * w.w;
            acc4[1][0] += a1 * w.x; acc4[1][1] += a1 * w.y; acc4[1][2] += a1 * w.z; acc4[1][3] += a1 * w.w;
            acc4[2][0] += a2 * w.x; acc4[2][1] += a2 * w.y; acc4[2][2] += a2 * w.z; acc4[2][3] += a2 * w.w;
            acc4[3][0] += a3 * w.x; acc4[3][1] += a3 * w.y; acc4[3][2] += a3 * w.z; acc4[3][3] += a3 * w.w;
        }
        __syncthreads();
    }

    // epilogue
#pragma unroll
    for (int r = 0; r < 4; ++r) {
        int grow = brow + ty * 4 + r;
#pragma unroll
        for (int c = 0; c < 4; ++c) {
            int gcol = bcol + tx * 4 + c;
            if (gcol < N) {
                size_t idx = (size_t)grow * N + gcol;
                float v = acc4[r][c];
                if (acc)  v += C[idx];
                if (bias) v += bias[gcol];
                if (act == 1) v = fmaxf(v, 0.f);
                C[idx] = v;
            }
        }
    }
}

// ---------------------------------------------------------------------------
// int_imp[b,a] = softmax_a( mean_c (tar[b,a,c]-pred[b,a,c])^2 )
// One wave (64 threads) per b.
// ---------------------------------------------------------------------------
__global__ __launch_bounds__(64)
void mse_softmax(const float* __restrict__ tar, const float* __restrict__ pred,
                 float* __restrict__ int_imp)
{
    const int b    = blockIdx.x;
    const int lane = threadIdx.x;
    __shared__ float m[AA];

    for (int a = 0; a < AA; ++a) {
        const float* t = tar  + ((size_t)b * AA + a) * CUR_OUT;
        const float* p = pred + ((size_t)b * AA + a) * CUR_OUT;
        float s = 0.f;
        for (int c = lane; c < CUR_OUT; c += 64) {
            float d = t[c] - p[c];
            s += d * d;
        }
#pragma unroll
        for (int off = 32; off > 0; off >>= 1) s += __shfl_down(s, off);
        if (lane == 0) m[a] = s * (1.f / CUR_OUT);
    }
    __syncthreads();
    if (lane == 0) {
        float mx = -1e30f;
#pragma unroll
        for (int a = 0; a < AA; ++a) mx = fmaxf(mx, m[a]);
        float e[AA];
        float den = 0.f;
#pragma unroll
        for (int a = 0; a < AA; ++a) { e[a] = __expf(m[a] - mx); den += e[a]; }
        float inv = 1.f / den;
#pragma unroll
        for (int a = 0; a < AA; ++a) int_imp[(size_t)b * AA + a] = e[a] * inv;
    }
}

// ---------------------------------------------------------------------------
// Per-b attention: logits[i,j] = qpart[b,i,j] + kpart[b,j] + ba[j]
//   attn[i,j] = softmax_j(logits[i,:]) + 0.5*int_imp[b,j]
//   applied[b,i,v] = sum_j attn[i,j] * value[b,j,v]
// One block (256 threads) per b.
// ---------------------------------------------------------------------------
__global__ __launch_bounds__(256)
void attn_apply(const float* __restrict__ qpart, const float* __restrict__ kpart,
                const float* __restrict__ ba,    const float* __restrict__ int_imp,
                const float* __restrict__ value, float* __restrict__ applied)
{
    const int b   = blockIdx.x;
    const int tid = threadIdx.x;
    __shared__ float vlds[AA * NV];       // 16x128
    __shared__ float attn[AA][AA + 1];

    for (int i = tid; i < AA * NV; i += 256)
        vlds[i] = value[(size_t)b * (AA * NV) + i];

    if (tid < AA) {
        const int i = tid;
        float l[AA];
        float mx = -1e30f;
#pragma unroll
        for (int j = 0; j < AA; ++j) {
            l[j] = qpart[((size_t)b * AA + i) * AA + j] + kpart[(size_t)b * AA + j] + ba[j];
            mx = fmaxf(mx, l[j]);
        }
        float den = 0.f;
#pragma unroll
        for (int j = 0; j < AA; ++j) { l[j] = __expf(l[j] - mx); den += l[j]; }
        float inv = 1.f / den;
#pragma unroll
        for (int j = 0; j < AA; ++j)
            attn[i][j] = l[j] * inv + 0.5f * int_imp[(size_t)b * AA + j];
    }
    __syncthreads();

    for (int o = tid; o < AA * NV; o += 256) {
        int i = o >> 7;       // /128
        int v = o & 127;
        float s = 0.f;
#pragma unroll
        for (int j = 0; j < AA; ++j) s += attn[i][j] * vlds[j * NV + v];
        applied[(size_t)b * (AA * NV) + o] = s;
    }
}

// ---------------------------------------------------------------------------
// Launch
// ---------------------------------------------------------------------------
extern "C" void kernel_launch(void* const* d_in, const int* in_sizes, int n_in,
                              void* d_out, int out_size, void* d_ws, size_t ws_size,
                              hipStream_t stream)
{
    const float* x      = (const float*)d_in[0];
    const float* hidden = (const float*)d_in[1];
    const float* Wk  = (const float*)d_in[2];
    const float* bk  = (const float*)d_in[3];
    const float* Wv  = (const float*)d_in[4];
    const float* bv  = (const float*)d_in[5];
    const float* Wq  = (const float*)d_in[6];
    const float* bq  = (const float*)d_in[7];
    const float* Wa  = (const float*)d_in[8];
    const float* ba  = (const float*)d_in[9];
    const float* Wt1 = (const float*)d_in[10];
    const float* bt1 = (const float*)d_in[11];
    const float* Wt2 = (const float*)d_in[12];
    const float* bt2 = (const float*)d_in[13];
    const float* Wp1 = (const float*)d_in[14];
    const float* bp1 = (const float*)d_in[15];
    const float* Wp2 = (const float*)d_in[16];
    const float* bp2 = (const float*)d_in[17];
    const float* Wp3 = (const float*)d_in[18];
    const float* bp3 = (const float*)d_in[19];
    const float* Wc  = (const float*)d_in[20];
    const float* bc  = (const float*)d_in[21];
    const float* W2  = (const float*)d_in[22];
    const float* b2  = (const float*)d_in[23];

    float* out = (float*)d_out;
    float* ws  = (float*)d_ws;

    // ---- workspace layout (floats) -------------------------------------
    float* bufA = ws;                                  // BA*512
    float* bufB = bufA + (size_t)BA * 512;             // BA*512
    float* tar  = bufB + (size_t)BA * 512;             // BA*128
    float* iimp = tar  + (size_t)BA * 128;             // B*A
    // phase-2 reuse of bufA/bufB region:
    float* key     = bufA;                             // BA*32
    float* value   = key     + (size_t)BA * 32;        // BA*128
    float* query   = value   + (size_t)BA * 128;       // BA*32
    float* qpart   = query   + (size_t)BA * 32;        // BA*16
    float* kpart   = qpart   + (size_t)BA * 16;        // B*16
    float* applied = kpart   + (size_t)BB * 16;        // BA*128
    float* comb    = applied + (size_t)BA * 128;       // BA*256

    const dim3 blk(256);
    const int gy = BA / TILE_M;   // 2048

    // ---- phase 1: intrinsic-motivation predictors ----------------------
    // h_t = relu(x@Wt1+bt1)            -> bufA
    gemm_f32<<<dim3(CUR_HID / TILE_N, gy), blk, 0, stream>>>(x, Wt1, bt1, bufA, BA, CUR_HID, IN_DIM, CUR_HID, 1, 0);
    // tar = h_t@Wt2+bt2                -> tar
    gemm_f32<<<dim3(CUR_OUT / TILE_N, gy), blk, 0, stream>>>(bufA, Wt2, bt2, tar, BA, CUR_OUT, CUR_HID, CUR_OUT, 0, 0);
    // h_p1 = relu(x@Wp1+bp1)           -> bufB
    gemm_f32<<<dim3(CUR_HID / TILE_N, gy), blk, 0, stream>>>(x, Wp1, bp1, bufB, BA, CUR_HID, IN_DIM, CUR_HID, 1, 0);
    // h_p2 = relu(h_p1@Wp2+bp2)        -> bufA
    gemm_f32<<<dim3(CUR_HID / TILE_N, gy), blk, 0, stream>>>(bufB, Wp2, bp2, bufA, BA, CUR_HID, CUR_HID, CUR_HID, 1, 0);
    // pred = h_p2@Wp3+bp3              -> bufB (reuse)
    gemm_f32<<<dim3(CUR_OUT / TILE_N, gy), blk, 0, stream>>>(bufA, Wp3, bp3, bufB, BA, CUR_OUT, CUR_HID, CUR_OUT, 0, 0);
    // int_imp = softmax(mean((tar-pred)^2))
    mse_softmax<<<BB, 64, 0, stream>>>(tar, bufB, iimp);

    // ---- phase 2: communicate() ----------------------------------------
    gemm_f32<<<dim3(1, gy), blk, 0, stream>>>(hidden, Wk, bk, key,   BA, NK, HID, NK, 0, 0);
    gemm_f32<<<dim3(NV / TILE_N, gy), blk, 0, stream>>>(hidden, Wv, bv, value, BA, NV, HID, NV, 0, 0);
    gemm_f32<<<dim3(1, gy), blk, 0, stream>>>(hidden, Wq, bq, query, BA, NQ, HID, NQ, 0, 0);
    // qpart = query @ Wa[:NQ,:]   (no bias; ba added in attn kernel)
    gemm_f32<<<dim3(1, gy), blk, 0, stream>>>(query, Wa, nullptr, qpart, BA, AA, NQ, AA, 0, 0);
    // kpart = flat_key @ Wa[NQ:,:]  (flat_key = key viewed as [B, A*NK])
    gemm_f32<<<dim3(1, BB / TILE_M), blk, 0, stream>>>(key, Wa + NQ * AA, nullptr, kpart, BB, AA, AA * NK, AA, 0, 0);
    // attention + apply to value
    attn_apply<<<BB, 256, 0, stream>>>(qpart, kpart, ba, iimp, value, applied);

    // ---- phase 3: combine + output head --------------------------------
    // comb = applied @ Wc[:NV,:]
    gemm_f32<<<dim3(HID / TILE_N, gy), blk, 0, stream>>>(applied, Wc, nullptr, comb, BA, HID, NV, HID, 0, 0);
    // comb = relu(comb + hidden @ Wc[NV:,:] + bc)
    gemm_f32<<<dim3(HID / TILE_N, gy), blk, 0, stream>>>(hidden, Wc + NV * HID, bc, comb, BA, HID, HID, HID, 1, 1);
    // out = comb @ W2 + b2
    gemm_f32<<<dim3(1, gy), blk, 0, stream>>>(comb, W2, b2, out, BA, N_ACT, HID, N_ACT, 0, 0);
}

// Round 2
// 905.076 us; speedup vs baseline: 7.6744x; 7.6744x over previous
//
#include <hip/hip_runtime.h>
#include <cstddef>
#include <cstdint>

typedef unsigned short ushort_t;
typedef __attribute__((ext_vector_type(4))) float f32x4;
typedef __attribute__((ext_vector_type(8))) short bf16x8;

#define BB   8192
#define AA   16
#define BA   131072
#define HID  256
#define NK   32
#define NQ   32
#define NV   128
#define IN_DIM  512
#define CUR_HID 512
#define CUR_OUT 128
#define N_ACT   64

// ---------------------------------------------------------------------------
// bf16 helpers (raw-bits ushort representation everywhere)
// ---------------------------------------------------------------------------
__device__ __forceinline__ float bf2f(ushort_t u) {
    union { float f; uint32_t i; } v; v.i = ((uint32_t)u) << 16; return v.f;
}
__device__ __forceinline__ ushort_t f2bf(float f) {
    union { float f; uint32_t i; } v; v.f = f;
    uint32_t r = v.i + 0x7fffu + ((v.i >> 16) & 1u);   // round-nearest-even
    return (ushort_t)(r >> 16);
}

__device__ __forceinline__ void gload_lds16(const void* g, void* l) {
    __builtin_amdgcn_global_load_lds(
        (const __attribute__((address_space(1))) uint32_t*)g,
        (__attribute__((address_space(3))) uint32_t*)l, 16, 0, 0);
}

// ---------------------------------------------------------------------------
// MFMA GEMM: C[M,N] = epilogue( A[M,K](bf16, row stride lda) @ Bt^T + bias )
//   Bt is [Npad][K] bf16 = W^T, Npad multiple of 128 (zero padded rows).
//   M multiple of 128, K multiple of 64. Tile 128x128, BK=64, 4 waves.
//   OBF16: write bf16, else f32.  RELU: max(0,.)
// ---------------------------------------------------------------------------
template<bool OBF16, bool RELU>
__global__ __launch_bounds__(256)
void gemm_mfma(const ushort_t* __restrict__ A, int lda,
               const ushort_t* __restrict__ Bt,
               const float* __restrict__ bias,
               void* __restrict__ C, int N, int K)
{
    __shared__ ushort_t As[128 * 64];
    __shared__ ushort_t Bs[128 * 64];

    const int tid  = threadIdx.x;
    const int w    = tid >> 6;
    const int lane = tid & 63;
    const int wm   = w >> 1;            // wave row (0..1)
    const int wn   = w & 1;             // wave col (0..1)
    const size_t brow = (size_t)blockIdx.y * 128;
    const int    bcol = blockIdx.x * 128;

    const int fr = lane & 15;           // fragment row/col index
    const int fq = lane >> 4;           // quad 0..3

    f32x4 acc[4][4];
#pragma unroll
    for (int i = 0; i < 4; ++i)
#pragma unroll
        for (int j = 0; j < 4; ++j) acc[i][j] = (f32x4){0.f, 0.f, 0.f, 0.f};

    // staging geometry: chunk c covers LDS rows c*8..c*8+8 of a [128][64] tile
    const int srow = lane >> 3;         // 0..7 within chunk
    const int scol = (lane & 7) << 3;   // 0,8,..,56

    for (int k0 = 0; k0 < K; k0 += 64) {
#pragma unroll
        for (int i = 0; i < 4; ++i) {
            const int c = (w << 2) + i;             // chunk 0..15
            const int r = (c << 3) + srow;          // tile row 0..127
            gload_lds16(A  + (brow + r) * (size_t)lda + k0 + scol,
                        &As[(c << 9) + lane * 8]);
            gload_lds16(Bt + (size_t)(bcol + r) * K + k0 + scol,
                        &Bs[(c << 9) + lane * 8]);
        }
        __syncthreads();   // drains vmcnt(0): tiles resident

#pragma unroll
        for (int kk = 0; kk < 2; ++kk) {
            bf16x8 a[4], b[4];
#pragma unroll
            for (int f = 0; f < 4; ++f) {
                a[f] = *(const bf16x8*)&As[(wm * 64 + f * 16 + fr) * 64 + kk * 32 + fq * 8];
                b[f] = *(const bf16x8*)&Bs[(wn * 64 + f * 16 + fr) * 64 + kk * 32 + fq * 8];
            }
#pragma unroll
            for (int fm = 0; fm < 4; ++fm)
#pragma unroll
                for (int fn = 0; fn < 4; ++fn)
                    acc[fm][fn] = __builtin_amdgcn_mfma_f32_16x16x32_bf16(
                        a[fm], b[fn], acc[fm][fn], 0, 0, 0);
        }
        __syncthreads();
    }

    // epilogue: C/D layout col=lane&15, row=(lane>>4)*4+r  [measured m89/m91]
#pragma unroll
    for (int fm = 0; fm < 4; ++fm) {
        const size_t rowb = brow + wm * 64 + fm * 16 + fq * 4;
#pragma unroll
        for (int fn = 0; fn < 4; ++fn) {
            const int col = bcol + wn * 64 + fn * 16 + fr;
            if (col < N) {
                const float bv = bias[col];
#pragma unroll
                for (int r = 0; r < 4; ++r) {
                    float v = acc[fm][fn][r] + bv;
                    if (RELU) v = fmaxf(v, 0.f);
                    const size_t idx = (rowb + r) * (size_t)N + col;
                    if (OBF16) ((ushort_t*)C)[idx] = f2bf(v);
                    else       ((float*)C)[idx]    = v;
                }
            }
        }
    }
}

// ---------------------------------------------------------------------------
// weight transpose+convert: Wt[n][k] = bf16(W[k][n]), zero pad n in [N,Npad)
// ---------------------------------------------------------------------------
__global__ __launch_bounds__(256)
void transpose_w(const float* __restrict__ W, ushort_t* __restrict__ Wt,
                 int K, int N, int Npad)
{
    int idx = blockIdx.x * 256 + threadIdx.x;
    if (idx >= Npad * K) return;
    int n = idx / K, k = idx - n * K;
    float v = (n < N) ? W[(size_t)k * N + n] : 0.f;
    Wt[idx] = f2bf(v);
}

// x: f32 contiguous -> bf16 contiguous (float4 per thread)
__global__ __launch_bounds__(256)
void conv_x(const float* __restrict__ src, ushort_t* __restrict__ dst)
{
    size_t q = (size_t)blockIdx.x * 256 + threadIdx.x;  // 16777216 quads
    float4 v = ((const float4*)src)[q];
    ushort_t* d = dst + q * 4;
    d[0] = f2bf(v.x); d[1] = f2bf(v.y); d[2] = f2bf(v.z); d[3] = f2bf(v.w);
}

// hidden [131072][256] f32 -> comb_in cols 128..384 (row stride 384) bf16
__global__ __launch_bounds__(256)
void conv_hidden(const float* __restrict__ src, ushort_t* __restrict__ comb_in)
{
    size_t q = (size_t)blockIdx.x * 256 + threadIdx.x;  // 8388608 quads
    size_t row = q >> 6;
    int c4 = (int)(q & 63) << 2;
    float4 v = *(const float4*)(src + row * 256 + c4);
    ushort_t* d = comb_in + row * 384 + 128 + c4;
    d[0] = f2bf(v.x); d[1] = f2bf(v.y); d[2] = f2bf(v.z); d[3] = f2bf(v.w);
}

// ---------------------------------------------------------------------------
// int_imp[b,a] = softmax_a( mean_c (tar-pred)^2 ), bf16 inputs
// ---------------------------------------------------------------------------
__global__ __launch_bounds__(64)
void mse_softmax(const ushort_t* __restrict__ tar, const ushort_t* __restrict__ pred,
                 float* __restrict__ int_imp)
{
    const int b = blockIdx.x, lane = threadIdx.x;
    __shared__ float m[AA];
    for (int a = 0; a < AA; ++a) {
        const ushort_t* t = tar  + ((size_t)b * AA + a) * CUR_OUT;
        const ushort_t* p = pred + ((size_t)b * AA + a) * CUR_OUT;
        float s = 0.f;
#pragma unroll
        for (int i = 0; i < 2; ++i) {
            int c = lane + i * 64;
            float d = bf2f(t[c]) - bf2f(p[c]);
            s += d * d;
        }
#pragma unroll
        for (int off = 32; off > 0; off >>= 1) s += __shfl_down(s, off);
        if (lane == 0) m[a] = s * (1.f / CUR_OUT);
    }
    __syncthreads();
    if (lane == 0) {
        float mx = -1e30f;
#pragma unroll
        for (int a = 0; a < AA; ++a) mx = fmaxf(mx, m[a]);
        float e[AA], den = 0.f;
#pragma unroll
        for (int a = 0; a < AA; ++a) { e[a] = __expf(m[a] - mx); den += e[a]; }
        float inv = 1.f / den;
#pragma unroll
        for (int a = 0; a < AA; ++a) int_imp[(size_t)b * AA + a] = e[a] * inv;
    }
}

// ---------------------------------------------------------------------------
// attention: folds qpart/kpart (qk @ Wa), softmax, +0.5*int_imp, apply to V.
// writes applied into comb_in cols 0..128 (row stride 384). one block per b.
// ---------------------------------------------------------------------------
__global__ __launch_bounds__(256)
void attn_apply(const ushort_t* __restrict__ qry, const ushort_t* __restrict__ key,
                const ushort_t* __restrict__ val, const float* __restrict__ Wa,
                const float* __restrict__ ba, const float* __restrict__ iimp,
                ushort_t* __restrict__ comb_in)
{
    const int b = blockIdx.x, t = threadIdx.x;
    __shared__ float klds[512], qlds[512];
    __shared__ ushort_t vlds[2048];
    __shared__ float part[16][17];
    __shared__ float kp[16];
    __shared__ float attn[16][17];

    for (int i = t; i < 512; i += 256) {
        klds[i] = bf2f(key[(size_t)b * 512 + i]);
        qlds[i] = bf2f(qry[(size_t)b * 512 + i]);
    }
    for (int i = t; i < 2048; i += 256) vlds[i] = val[(size_t)b * 2048 + i];
    __syncthreads();

    // kpart[j] = sum_c flat_key[c] * Wa[32+c][j]   (per-b, independent of i)
    {
        int j = t & 15, seg = t >> 4;
        float s = 0.f;
        for (int c = seg * 32; c < seg * 32 + 32; ++c)
            s += klds[c] * Wa[(32 + c) * 16 + j];
        part[j][seg] = s;
    }
    __syncthreads();
    if (t < 16) {
        float s = 0.f;
#pragma unroll
        for (int seg = 0; seg < 16; ++seg) s += part[t][seg];
        kp[t] = s;
    }
    __syncthreads();

    // logits[i][j] = query[i,:] @ Wa[:32,j] + kpart[j] + ba[j]
    {
        int i = t >> 4, j = t & 15;
        float s = 0.f;
#pragma unroll
        for (int q = 0; q < 32; ++q) s += qlds[i * 32 + q] * Wa[q * 16 + j];
        attn[i][j] = s + kp[j] + ba[j];
    }
    __syncthreads();
    if (t < 16) {
        float mx = -1e30f;
#pragma unroll
        for (int j = 0; j < 16; ++j) mx = fmaxf(mx, attn[t][j]);
        float e[16], den = 0.f;
#pragma unroll
        for (int j = 0; j < 16; ++j) { e[j] = __expf(attn[t][j] - mx); den += e[j]; }
        float inv = 1.f / den;
#pragma unroll
        for (int j = 0; j < 16; ++j)
            attn[t][j] = e[j] * inv + 0.5f * iimp[b * 16 + j];
    }
    __syncthreads();

    for (int o = t; o < 2048; o += 256) {
        int i = o >> 7, v = o & 127;
        float s = 0.f;
#pragma unroll
        for (int j = 0; j < 16; ++j) s += attn[i][j] * bf2f(vlds[j * 128 + v]);
        comb_in[(size_t)(b * 16 + i) * 384 + v] = f2bf(s);
    }
}

// ---------------------------------------------------------------------------
// launch
// ---------------------------------------------------------------------------
extern "C" void kernel_launch(void* const* d_in, const int* in_sizes, int n_in,
                              void* d_out, int out_size, void* d_ws, size_t ws_size,
                              hipStream_t stream)
{
    const float* x      = (const float*)d_in[0];
    const float* hidden = (const float*)d_in[1];
    const float* Wk  = (const float*)d_in[2];
    const float* bk  = (const float*)d_in[3];
    const float* Wv  = (const float*)d_in[4];
    const float* bv  = (const float*)d_in[5];
    const float* Wq  = (const float*)d_in[6];
    const float* bq  = (const float*)d_in[7];
    const float* Wa  = (const float*)d_in[8];
    const float* ba  = (const float*)d_in[9];
    const float* Wt1 = (const float*)d_in[10];
    const float* bt1 = (const float*)d_in[11];
    const float* Wt2 = (const float*)d_in[12];
    const float* bt2 = (const float*)d_in[13];
    const float* Wp1 = (const float*)d_in[14];
    const float* bp1 = (const float*)d_in[15];
    const float* Wp2 = (const float*)d_in[16];
    const float* bp2 = (const float*)d_in[17];
    const float* Wp3 = (const float*)d_in[18];
    const float* bp3 = (const float*)d_in[19];
    const float* Wc  = (const float*)d_in[20];
    const float* bc  = (const float*)d_in[21];
    const float* W2  = (const float*)d_in[22];
    const float* b2  = (const float*)d_in[23];

    float*    out = (float*)d_out;
    ushort_t* ws  = (ushort_t*)d_ws;

    // ---- workspace (bf16 element offsets) -------------------------------
    ushort_t* xb = ws;                              // [BA*512]; later reused as h_p2
    ushort_t* P1 = xb + (size_t)BA * 512;           // h_t; later phase-2 pool
    ushort_t* P2 = P1 + (size_t)BA * 512;           // h_p1; later comb_in
    ushort_t* T  = P2 + (size_t)BA * 512;           // tar  [BA*128]
    ushort_t* PR = T  + (size_t)BA * 128;           // pred [BA*128]
    ushort_t* WT = PR + (size_t)BA * 128;           // weights region
    // phase-2 aliases
    ushort_t* key     = P1;                         // BA*32
    ushort_t* qry     = key + (size_t)BA * 32;      // BA*32
    ushort_t* val     = qry + (size_t)BA * 32;      // BA*128
    ushort_t* comb    = val + (size_t)BA * 128;     // BA*256
    ushort_t* comb_in = P2;                         // BA*384 (applied|hidden)
    ushort_t* hp2     = xb;                         // h_p2 overwrites xb after G3

    // transposed bf16 weights (padded to 128-row multiples)
    ushort_t* Wt1t = WT;                  // 512*512
    ushort_t* Wt2t = Wt1t + 512 * 512;    // 128*512
    ushort_t* Wp1t = Wt2t + 128 * 512;    // 512*512
    ushort_t* Wp2t = Wp1t + 512 * 512;    // 512*512
    ushort_t* Wp3t = Wp2t + 512 * 512;    // 128*512
    ushort_t* Wkt  = Wp3t + 128 * 512;    // 128*256 (N=32 padded)
    ushort_t* Wvt  = Wkt  + 128 * 256;    // 128*256
    ushort_t* Wqt  = Wvt  + 128 * 256;    // 128*256 (N=32 padded)
    ushort_t* Wct  = Wqt  + 128 * 256;    // 256*384
    ushort_t* W2t  = Wct  + 256 * 384;    // 128*256 (N=64 padded)
    float*    iimp = (float*)(W2t + 128 * 256 + 128); // [BB*AA] (aligned)

    const dim3 blk(256);
    const int gy = BA / 128;  // 1024

    // ---- conversions / transposes ---------------------------------------
    conv_x<<<65536, blk, 0, stream>>>(x, xb);
    transpose_w<<<(512 * 512 + 255) / 256, blk, 0, stream>>>(Wt1, Wt1t, 512, 512, 512);
    transpose_w<<<(128 * 512 + 255) / 256, blk, 0, stream>>>(Wt2, Wt2t, 512, 128, 128);
    transpose_w<<<(512 * 512 + 255) / 256, blk, 0, stream>>>(Wp1, Wp1t, 512, 512, 512);
    transpose_w<<<(512 * 512 + 255) / 256, blk, 0, stream>>>(Wp2, Wp2t, 512, 512, 512);
    transpose_w<<<(128 * 512 + 255) / 256, blk, 0, stream>>>(Wp3, Wp3t, 512, 128, 128);
    transpose_w<<<(128 * 256 + 255) / 256, blk, 0, stream>>>(Wk,  Wkt,  256, 32, 128);
    transpose_w<<<(128 * 256 + 255) / 256, blk, 0, stream>>>(Wv,  Wvt,  256, 128, 128);
    transpose_w<<<(128 * 256 + 255) / 256, blk, 0, stream>>>(Wq,  Wqt,  256, 32, 128);
    transpose_w<<<(256 * 384 + 255) / 256, blk, 0, stream>>>(Wc,  Wct,  384, 256, 256);
    transpose_w<<<(128 * 256 + 255) / 256, blk, 0, stream>>>(W2,  W2t,  256, 64, 128);

    // ---- phase 1: predictors --------------------------------------------
    gemm_mfma<true, true ><<<dim3(4, gy), blk, 0, stream>>>(xb, 512, Wt1t, bt1, P1, 512, 512); // h_t
    gemm_mfma<true, false><<<dim3(1, gy), blk, 0, stream>>>(P1, 512, Wt2t, bt2, T, 128, 512);  // tar
    gemm_mfma<true, true ><<<dim3(4, gy), blk, 0, stream>>>(xb, 512, Wp1t, bp1, P2, 512, 512); // h_p1
    gemm_mfma<true, true ><<<dim3(4, gy), blk, 0, stream>>>(P2, 512, Wp2t, bp2, hp2, 512, 512);// h_p2
    gemm_mfma<true, false><<<dim3(1, gy), blk, 0, stream>>>(hp2, 512, Wp3t, bp3, PR, 128, 512);// pred
    mse_softmax<<<BB, 64, 0, stream>>>(T, PR, iimp);

    // ---- phase 2: communicate -------------------------------------------
    conv_hidden<<<32768, blk, 0, stream>>>(hidden, comb_in);
    const ushort_t* hb = comb_in + 128;   // hidden bf16, lda = 384
    gemm_mfma<true, false><<<dim3(1, gy), blk, 0, stream>>>(hb, 384, Wkt, bk, key, 32, 256);
    gemm_mfma<true, false><<<dim3(1, gy), blk, 0, stream>>>(hb, 384, Wvt, bv, val, 128, 256);
    gemm_mfma<true, false><<<dim3(1, gy), blk, 0, stream>>>(hb, 384, Wqt, bq, qry, 32, 256);
    attn_apply<<<BB, blk, 0, stream>>>(qry, key, val, Wa, ba, iimp, comb_in);

    // ---- phase 3: combine + head ----------------------------------------
    gemm_mfma<true, true ><<<dim3(2, gy), blk, 0, stream>>>(comb_in, 384, Wct, bc, comb, 256, 384);
    gemm_mfma<false, false><<<dim3(1, gy), blk, 0, stream>>>(comb, 256, W2t, b2, out, 64, 256);
}

// Round 3
// 849.219 us; speedup vs baseline: 8.1791x; 1.0658x over previous
//
#include <hip/hip_runtime.h>
#include <cstddef>
#include <cstdint>

typedef unsigned short ushort_t;
typedef __attribute__((ext_vector_type(4))) float f32x4;
typedef __attribute__((ext_vector_type(8))) short bf16x8;

#define BB   8192
#define AA   16
#define BA   131072
#define HID  256
#define NV   128

// ---------------------------------------------------------------------------
// bf16 helpers
// ---------------------------------------------------------------------------
__device__ __forceinline__ float bf2f(ushort_t u) {
    union { float f; uint32_t i; } v; v.i = ((uint32_t)u) << 16; return v.f;
}
__device__ __forceinline__ ushort_t f2bf(float f) {
    union { float f; uint32_t i; } v; v.f = f;
    uint32_t r = v.i + 0x7fffu + ((v.i >> 16) & 1u);
    return (ushort_t)(r >> 16);
}
__device__ __forceinline__ void gload_lds16(const void* g, void* l) {
    __builtin_amdgcn_global_load_lds(
        (const __attribute__((address_space(1))) uint32_t*)g,
        (__attribute__((address_space(3))) uint32_t*)l, 16, 0, 0);
}

// ---------------------------------------------------------------------------
// MFMA GEMM, 128x128 tile, BK=64, 4 waves, double-buffered LDS with
// prefetch-before-compute (T3 minimal recipe: one barrier per K-step).
// Grid is 1-D = 1024*gx blocks with XCD-panel swizzle: the gx column-blocks
// of one 128-row A panel land adjacently on the SAME XCD (A fetched once).
//   A rows: k < ksplit from A(lda), k >= ksplit from A2(lda2)  [concat fusion]
//   Bt: [Npad>=128*gx][K] = W^T zero-padded. C row stride ldc. M = 131072.
// ---------------------------------------------------------------------------
template<bool OBF16, bool RELU>
__global__ __launch_bounds__(256)
void gemm_mfma(const ushort_t* __restrict__ A, int lda,
               const ushort_t* __restrict__ A2, int lda2, int ksplit,
               const ushort_t* __restrict__ Bt,
               const float* __restrict__ bias,
               void* __restrict__ C, int ldc, int N, int K, int lgx)
{
    __shared__ ushort_t As[2][128 * 64];
    __shared__ ushort_t Bs[2][128 * 64];

    const int tid  = threadIdx.x;
    const int w    = tid >> 6;
    const int lane = tid & 63;
    const int wm   = w >> 1;
    const int wn   = w & 1;

    // XCD-panel swizzle (bijective; grid = 8 * 128 * gx)
    const int bid  = blockIdx.x;
    const int xcd  = bid & 7;
    const int slot = bid >> 3;
    const int x    = slot & ((1 << lgx) - 1);
    const int y    = xcd * 128 + (slot >> lgx);
    const size_t brow = (size_t)y * 128;
    const int    bcol = x * 128;

    const int fr   = lane & 15;
    const int fq   = lane >> 4;
    const int srow = lane >> 3;          // staging row within 8-row chunk
    const int scol = (lane & 7) << 3;    // staging col (elements)

    f32x4 acc[4][4];
#pragma unroll
    for (int i = 0; i < 4; ++i)
#pragma unroll
        for (int j = 0; j < 4; ++j) acc[i][j] = (f32x4){0.f, 0.f, 0.f, 0.f};

    const int NT = K >> 6;

    auto stage = [&](int buf, int k0) {
#pragma unroll
        for (int i = 0; i < 4; ++i) {
            const int c = (w << 2) + i;          // chunk 0..15
            const int r = (c << 3) + srow;       // tile row 0..127
            const ushort_t* asrc;
            if (k0 >= ksplit)
                asrc = A2 + (brow + r) * (size_t)lda2 + (k0 - ksplit) + scol;
            else
                asrc = A  + (brow + r) * (size_t)lda  + k0 + scol;
            gload_lds16(asrc, &As[buf][(c << 9) + lane * 8]);
            gload_lds16(Bt + (size_t)(bcol + r) * K + k0 + scol,
                        &Bs[buf][(c << 9) + lane * 8]);
        }
    };

    stage(0, 0);
    __syncthreads();                       // tile 0 resident

    for (int t = 0; t < NT; ++t) {
        const int cur = t & 1;
        if (t + 1 < NT) stage(cur ^ 1, (t + 1) << 6);   // prefetch next tile
#pragma unroll
        for (int kk = 0; kk < 2; ++kk) {
            bf16x8 a[4], b[4];
#pragma unroll
            for (int f = 0; f < 4; ++f) {
                a[f] = *(const bf16x8*)&As[cur][(wm * 64 + f * 16 + fr) * 64 + kk * 32 + fq * 8];
                b[f] = *(const bf16x8*)&Bs[cur][(wn * 64 + f * 16 + fr) * 64 + kk * 32 + fq * 8];
            }
#pragma unroll
            for (int fm = 0; fm < 4; ++fm)
#pragma unroll
                for (int fn = 0; fn < 4; ++fn)
                    acc[fm][fn] = __builtin_amdgcn_mfma_f32_16x16x32_bf16(
                        a[fm], b[fn], acc[fm][fn], 0, 0, 0);
        }
        __syncthreads();   // drains vmcnt(0): prefetched tile resident; LDS reads done
    }

    // epilogue: C/D layout col=lane&15, row=(lane>>4)*4+r
#pragma unroll
    for (int fm = 0; fm < 4; ++fm) {
        const size_t rowb = brow + wm * 64 + fm * 16 + fq * 4;
#pragma unroll
        for (int fn = 0; fn < 4; ++fn) {
            const int col = bcol + wn * 64 + fn * 16 + fr;
            if (col < N) {
                const float bv = bias[col];
#pragma unroll
                for (int r = 0; r < 4; ++r) {
                    float v = acc[fm][fn][r] + bv;
                    if (RELU) v = fmaxf(v, 0.f);
                    const size_t idx = (rowb + r) * (size_t)ldc + col;
                    if (OBF16) ((ushort_t*)C)[idx] = f2bf(v);
                    else       ((float*)C)[idx]    = v;
                }
            }
        }
    }
}

// ---------------------------------------------------------------------------
// weight transpose+convert: Wt[n][k] = bf16(W[k][n]), zero-pad n in [N,Npad)
// ---------------------------------------------------------------------------
__global__ __launch_bounds__(256)
void transpose_w(const float* __restrict__ W, ushort_t* __restrict__ Wt,
                 int K, int N, int Npad)
{
    int idx = blockIdx.x * 256 + threadIdx.x;
    if (idx >= Npad * K) return;
    int n = idx / K, k = idx - n * K;
    float v = (n < N) ? W[(size_t)k * N + n] : 0.f;
    Wt[idx] = f2bf(v);
}

// signed transpose into K-concatenated slot: Wt[n*ldk + kOff + k] = sign*W[k][n]
__global__ __launch_bounds__(256)
void transpose_wk(const float* __restrict__ W, ushort_t* __restrict__ Wt,
                  int Ksrc, int N, int ldk, int kOff, float sign)
{
    int idx = blockIdx.x * 256 + threadIdx.x;
    if (idx >= N * Ksrc) return;
    int n = idx / Ksrc, k = idx - n * Ksrc;
    Wt[(size_t)n * ldk + kOff + k] = f2bf(sign * W[(size_t)k * N + n]);
}

// f32 contiguous -> bf16 contiguous, one float4 per thread
__global__ __launch_bounds__(256)
void conv_f32_bf16(const float* __restrict__ src, ushort_t* __restrict__ dst)
{
    size_t q = (size_t)blockIdx.x * 256 + threadIdx.x;
    float4 v = ((const float4*)src)[q];
    ushort_t* d = dst + q * 4;
    d[0] = f2bf(v.x); d[1] = f2bf(v.y); d[2] = f2bf(v.z); d[3] = f2bf(v.w);
}

// pbias = [bk(32) | bq(32) | bv(128) | 0(64)]
__global__ void pack_bias(const float* __restrict__ bk, const float* __restrict__ bq,
                          const float* __restrict__ bv, float* __restrict__ pb)
{
    int j = threadIdx.x;
    float v = 0.f;
    if      (j < 32)  v = bk[j];
    else if (j < 64)  v = bq[j - 32];
    else if (j < 192) v = bv[j - 64];
    pb[j] = v;
}

// cbias = bt2 - bp3
__global__ void make_cbias(const float* __restrict__ bt2, const float* __restrict__ bp3,
                           float* __restrict__ cb)
{
    int j = threadIdx.x;
    cb[j] = bt2[j] - bp3[j];
}

// ---------------------------------------------------------------------------
// int_imp[b,a] = softmax_a( mean_c diff[b,a,c]^2 ), diff bf16 [BB,AA,128]
// ---------------------------------------------------------------------------
__global__ __launch_bounds__(64)
void mse_softmax(const ushort_t* __restrict__ diff, float* __restrict__ int_imp)
{
    const int b = blockIdx.x, lane = threadIdx.x;
    __shared__ float m[AA];
    for (int a = 0; a < AA; ++a) {
        const uint32_t u = *(const uint32_t*)(diff + ((size_t)b * AA + a) * 128 + lane * 2);
        float d0 = bf2f((ushort_t)(u & 0xffff));
        float d1 = bf2f((ushort_t)(u >> 16));
        float s = d0 * d0 + d1 * d1;
#pragma unroll
        for (int off = 32; off > 0; off >>= 1) s += __shfl_down(s, off);
        if (lane == 0) m[a] = s * (1.f / 128.f);
    }
    __syncthreads();
    if (lane == 0) {
        float mx = -1e30f;
#pragma unroll
        for (int a = 0; a < AA; ++a) mx = fmaxf(mx, m[a]);
        float e[AA], den = 0.f;
#pragma unroll
        for (int a = 0; a < AA; ++a) { e[a] = __expf(m[a] - mx); den += e[a]; }
        float inv = 1.f / den;
#pragma unroll
        for (int a = 0; a < AA; ++a) int_imp[(size_t)b * AA + a] = e[a] * inv;
    }
}

// ---------------------------------------------------------------------------
// attention: kvq packed [BA][192] = [key(32)|qry(32)|val(128)] per row.
// folds qk@Wa, softmax, +0.5*iimp, apply to V; writes applied [BA][128] bf16.
// ---------------------------------------------------------------------------
__global__ __launch_bounds__(256)
void attn_apply(const ushort_t* __restrict__ kvq, const float* __restrict__ Wa,
                const float* __restrict__ ba, const float* __restrict__ iimp,
                ushort_t* __restrict__ applied)
{
    const int b = blockIdx.x, t = threadIdx.x;
    __shared__ float klds[512], qlds[512];
    __shared__ ushort_t vlds[2048];
    __shared__ float part[16][17];
    __shared__ float kp[16];
    __shared__ float attn[16][17];

    for (int i = t; i < 512; i += 256) {
        int a = i >> 5, c = i & 31;
        const size_t base = ((size_t)b * AA + a) * 192;
        klds[i] = bf2f(kvq[base + c]);
        qlds[i] = bf2f(kvq[base + 32 + c]);
    }
    for (int i = t; i < 2048; i += 256) {
        int j = i >> 7, v = i & 127;
        vlds[i] = kvq[((size_t)b * AA + j) * 192 + 64 + v];
    }
    __syncthreads();

    // kpart[j] = sum_c flat_key[c] * Wa[32+c][j]
    {
        int j = t & 15, seg = t >> 4;
        float s = 0.f;
        for (int c = seg * 32; c < seg * 32 + 32; ++c)
            s += klds[c] * Wa[(32 + c) * 16 + j];
        part[j][seg] = s;
    }
    __syncthreads();
    if (t < 16) {
        float s = 0.f;
#pragma unroll
        for (int seg = 0; seg < 16; ++seg) s += part[t][seg];
        kp[t] = s;
    }
    __syncthreads();

    // logits[i][j] = query[i,:] @ Wa[:32,j] + kpart[j] + ba[j]
    {
        int i = t >> 4, j = t & 15;
        float s = 0.f;
#pragma unroll
        for (int q = 0; q < 32; ++q) s += qlds[i * 32 + q] * Wa[q * 16 + j];
        attn[i][j] = s + kp[j] + ba[j];
    }
    __syncthreads();
    if (t < 16) {
        float mx = -1e30f;
#pragma unroll
        for (int j = 0; j < 16; ++j) mx = fmaxf(mx, attn[t][j]);
        float e[16], den = 0.f;
#pragma unroll
        for (int j = 0; j < 16; ++j) { e[j] = __expf(attn[t][j] - mx); den += e[j]; }
        float inv = 1.f / den;
#pragma unroll
        for (int j = 0; j < 16; ++j)
            attn[t][j] = e[j] * inv + 0.5f * iimp[b * 16 + j];
    }
    __syncthreads();

    for (int o = t; o < 2048; o += 256) {
        int i = o >> 7, v = o & 127;
        float s = 0.f;
#pragma unroll
        for (int j = 0; j < 16; ++j) s += attn[i][j] * bf2f(vlds[j * 128 + v]);
        applied[((size_t)b * AA + i) * 128 + v] = f2bf(s);
    }
}

// ---------------------------------------------------------------------------
// launch
// ---------------------------------------------------------------------------
extern "C" void kernel_launch(void* const* d_in, const int* in_sizes, int n_in,
                              void* d_out, int out_size, void* d_ws, size_t ws_size,
                              hipStream_t stream)
{
    const float* x      = (const float*)d_in[0];
    const float* hidden = (const float*)d_in[1];
    const float* Wk  = (const float*)d_in[2];
    const float* bk  = (const float*)d_in[3];
    const float* Wv  = (const float*)d_in[4];
    const float* bv  = (const float*)d_in[5];
    const float* Wq  = (const float*)d_in[6];
    const float* bq  = (const float*)d_in[7];
    const float* Wa  = (const float*)d_in[8];
    const float* ba  = (const float*)d_in[9];
    const float* Wt1 = (const float*)d_in[10];
    const float* bt1 = (const float*)d_in[11];
    const float* Wt2 = (const float*)d_in[12];
    const float* bt2 = (const float*)d_in[13];
    const float* Wp1 = (const float*)d_in[14];
    const float* bp1 = (const float*)d_in[15];
    const float* Wp2 = (const float*)d_in[16];
    const float* bp2 = (const float*)d_in[17];
    const float* Wp3 = (const float*)d_in[18];
    const float* bp3 = (const float*)d_in[19];
    const float* Wc  = (const float*)d_in[20];
    const float* bc  = (const float*)d_in[21];
    const float* W2  = (const float*)d_in[22];
    const float* b2  = (const float*)d_in[23];

    float*    out = (float*)d_out;
    ushort_t* ws  = (ushort_t*)d_ws;

    // ---- workspace layout (ushort elements) -----------------------------
    ushort_t* xb  = ws;                       // [BA*512] x bf16
    ushort_t* ht  = xb + (size_t)BA * 512;    // [BA*1024] = [h_t | h_p2]
    ushort_t* hp1 = ht + (size_t)BA * 1024;   // [BA*512] h_p1
    ushort_t* WT  = hp1 + (size_t)BA * 512;   // weights
    // aliases (ordered by liveness)
    ushort_t* diff    = xb;                   // BA*128 (after xb dead)
    ushort_t* kvq     = xb + (size_t)BA * 128;// BA*192
    ushort_t* hiddenb = hp1;                  // BA*256 (after h_p1 dead)
    ushort_t* applied = ht;                   // BA*128 (after ht dead)
    ushort_t* comb    = ht + (size_t)BA * 512;// BA*256

    ushort_t* Wt1t = WT;                    // 512*512
    ushort_t* Wp1t = Wt1t + 512 * 512;      // 512*512
    ushort_t* Wp2t = Wp1t + 512 * 512;      // 512*512
    ushort_t* Dt   = Wp2t + 512 * 512;      // 128*1024  [Wt2^T | -Wp3^T]
    ushort_t* Wkvq = Dt   + 128 * 1024;     // 256*256   [Wk|Wq|Wv]^T padded
    ushort_t* Wct  = Wkvq + 256 * 256;      // 256*384
    ushort_t* W2t  = Wct  + 256 * 384;      // 128*256
    float* pbias = (float*)(W2t + 128 * 256);
    float* cbias = pbias + 256;
    float* iimp  = cbias + 128;             // BB*AA floats

    const dim3 blk(256);
    const int BIG = 1 << 30;

    // ---- weight prep / conversions --------------------------------------
    conv_f32_bf16<<<65536, blk, 0, stream>>>(x, xb);                 // 16M quads
    transpose_w<<<1024, blk, 0, stream>>>(Wt1, Wt1t, 512, 512, 512);
    transpose_w<<<1024, blk, 0, stream>>>(Wp1, Wp1t, 512, 512, 512);
    transpose_w<<<1024, blk, 0, stream>>>(Wp2, Wp2t, 512, 512, 512);
    transpose_wk<<<256, blk, 0, stream>>>(Wt2, Dt, 512, 128, 1024, 0,    1.f);
    transpose_wk<<<256, blk, 0, stream>>>(Wp3, Dt, 512, 128, 1024, 512, -1.f);
    transpose_w<<<32,  blk, 0, stream>>>(Wk, Wkvq + 0 * 256,   256, 32, 32);
    transpose_w<<<32,  blk, 0, stream>>>(Wq, Wkvq + 32 * 256,  256, 32, 32);
    transpose_w<<<128, blk, 0, stream>>>(Wv, Wkvq + 64 * 256,  256, 128, 128);
    transpose_w<<<64,  blk, 0, stream>>>(Wk, Wkvq + 192 * 256, 256, 0, 64);   // zero pad
    transpose_w<<<384, blk, 0, stream>>>(Wc, Wct, 384, 256, 256);
    transpose_w<<<128, blk, 0, stream>>>(W2, W2t, 256, 64, 128);
    pack_bias<<<1, 256, 0, stream>>>(bk, bq, bv, pbias);
    make_cbias<<<1, 128, 0, stream>>>(bt2, bp3, cbias);

    // ---- phase 1: predictors --------------------------------------------
    // h_t = relu(x@Wt1+bt1) -> ht[:,0:512]
    gemm_mfma<true, true ><<<4096, blk, 0, stream>>>(xb, 512, xb, 512, BIG, Wt1t, bt1, ht, 1024, 512, 512, 2);
    // h_p1 = relu(x@Wp1+bp1) -> hp1
    gemm_mfma<true, true ><<<4096, blk, 0, stream>>>(xb, 512, xb, 512, BIG, Wp1t, bp1, hp1, 512, 512, 512, 2);
    // h_p2 = relu(h_p1@Wp2+bp2) -> ht[:,512:1024]
    gemm_mfma<true, true ><<<4096, blk, 0, stream>>>(hp1, 512, hp1, 512, BIG, Wp2t, bp2, ht + 512, 1024, 512, 512, 2);
    // hidden -> bf16 (overwrites hp1 region; h_p1 is dead)
    conv_f32_bf16<<<32768, blk, 0, stream>>>(hidden, hiddenb);       // 8M quads
    // diff = ht @ [Wt2;-Wp3] + (bt2-bp3)  (= tar - pred) -> diff
    gemm_mfma<true, false><<<1024, blk, 0, stream>>>(ht, 1024, ht, 1024, BIG, Dt, cbias, diff, 128, 128, 1024, 0);
    mse_softmax<<<BB, 64, 0, stream>>>(diff, iimp);

    // ---- phase 2: communicate -------------------------------------------
    // kvq = hidden @ [Wk|Wq|Wv] + pbias
    gemm_mfma<true, false><<<2048, blk, 0, stream>>>(hiddenb, 256, hiddenb, 256, BIG, Wkvq, pbias, kvq, 192, 192, 256, 1);
    attn_apply<<<BB, blk, 0, stream>>>(kvq, Wa, ba, iimp, applied);

    // ---- phase 3: combine + head ----------------------------------------
    // comb = relu([applied|hidden] @ Wc + bc)   (split-A: k<128 applied, k>=128 hidden)
    gemm_mfma<true, true ><<<2048, blk, 0, stream>>>(applied, 128, hiddenb, 256, 128, Wct, bc, comb, 256, 256, 384, 1);
    // out = comb @ W2 + b2  (f32 out)
    gemm_mfma<false, false><<<1024, blk, 0, stream>>>(comb, 256, comb, 256, BIG, W2t, b2, out, 64, 64, 256, 0);
}

// Round 4
// 694.265 us; speedup vs baseline: 10.0047x; 1.2232x over previous
//
#include <hip/hip_runtime.h>
#include <cstddef>
#include <cstdint>

typedef unsigned short ushort_t;
typedef __attribute__((ext_vector_type(4))) float f32x4;
typedef __attribute__((ext_vector_type(8))) short bf16x8;

#define BB   8192
#define AA   16
#define BA   131072
#define HID  256
#define NV   128

// ---------------------------------------------------------------------------
// bf16 helpers
// ---------------------------------------------------------------------------
__device__ __forceinline__ float bf2f(ushort_t u) {
    union { float f; uint32_t i; } v; v.i = ((uint32_t)u) << 16; return v.f;
}
__device__ __forceinline__ ushort_t f2bf(float f) {
    union { float f; uint32_t i; } v; v.f = f;
    uint32_t r = v.i + 0x7fffu + ((v.i >> 16) & 1u);
    return (ushort_t)(r >> 16);
}
__device__ __forceinline__ void gload_lds16(const void* g, void* l) {
    __builtin_amdgcn_global_load_lds(
        (const __attribute__((address_space(1))) uint32_t*)g,
        (__attribute__((address_space(3))) uint32_t*)l, 16, 0, 0);
}

// ---------------------------------------------------------------------------
// 256x256 MFMA GEMM, BK=32, 8 waves (2Mx4N), 4-deep LDS ring (128 KB),
// counted vmcnt (never 0 mid-loop), one raw s_barrier per K-tile,
// XOR-swizzled LDS (inverse-swizzled global source + swizzled ds_read).
//   A rows: k < ksplit from A(lda), else A2(lda2).  Bt: [N>=bcol+256][K].
//   M = 131072 rows. Output bf16 with bias+ReLU. ldc row stride.
// Grid: 8*rpx*(1<<lgx) blocks, XCD-panel swizzle.
// K-tile t lives in ring buffer t&3; stage(t+3) issued after the barrier
// that certifies all waves finished compute(t-1) (= last reader of buf t&3... 
// buf (t+3)&3 == buf (t-1)&3, whose readers all passed the iter-t barrier).
// vmcnt: at iter t, outstanding = 4*min(3, NT-t) own loads; waiting to
// 4*(min(3,NT-t)-1) guarantees tile t resident (m135 semantics).
// ---------------------------------------------------------------------------
__global__ __launch_bounds__(512)
void gemm256(const ushort_t* __restrict__ A, int lda,
             const ushort_t* __restrict__ A2, int lda2, int ksplit,
             const ushort_t* __restrict__ Bt,
             const float* __restrict__ bias,
             ushort_t* __restrict__ C, int ldc, int K, int lgx, int rpx)
{
    __shared__ ushort_t lds[65536];      // 4 bufs x (A 8192 + B 8192) ushorts

    const int tid  = threadIdx.x;
    const int w    = tid >> 6;
    const int lane = tid & 63;
    const int wm   = w >> 2;             // 0..1
    const int wn   = w & 3;              // 0..3
    const int fr   = lane & 15;
    const int fq   = lane >> 4;

    // XCD-panel swizzle
    const int bid  = blockIdx.x;
    const int xcd  = bid & 7;
    const int slot = bid >> 3;
    const int x    = slot & ((1 << lgx) - 1);
    const int y    = xcd * rpx + (slot >> lgx);
    const size_t brow = (size_t)y * 256;
    const int    bcol = x * 256;

    const int NT = K >> 5;

    f32x4 acc[8][4];
#pragma unroll
    for (int m = 0; m < 8; ++m)
#pragma unroll
        for (int n = 0; n < 4; ++n) acc[m][n] = (f32x4){0.f, 0.f, 0.f, 0.f};

    // stage one 256x32 A-tile + 256x32 B-tile into ring buffer `buf`.
    // granule = 16B = 8 elems; 2048 granules; thread covers 4 (rounds).
    // physical granule (row, g) holds logical col8 = g ^ s(row),
    // s(row) = (row ^ (row>>2)) & 3  -> read-side 2-way conflict max.
    auto stage = [&](int buf, int k0) {
        const int base = buf << 14;      // *16384 ushorts
#pragma unroll
        for (int r = 0; r < 4; ++r) {
            const int gamma = r * 512 + tid;         // 0..2047
            const int gi    = gamma & 1023;
            const int row   = gi >> 2;               // 0..255
            const int g     = gi & 3;
            const int s     = (row ^ (row >> 2)) & 3;
            const int col   = ((g ^ s) << 3);        // element col 0..24
            const ushort_t* src;
            if (gamma >= 1024) {
                src = Bt + (size_t)(bcol + row) * K + k0 + col;
            } else if (k0 >= ksplit) {
                src = A2 + (brow + row) * (size_t)lda2 + (k0 - ksplit) + col;
            } else {
                src = A  + (brow + row) * (size_t)lda  + k0 + col;
            }
            gload_lds16(src, &lds[base + gamma * 8]);
        }
    };

    // prologue: 3 tiles in flight
    stage(0, 0);
    if (NT > 1) stage(1, 32);
    if (NT > 2) stage(2, 64);

    const int sa = (fr ^ (fr >> 2)) & 3;
    const int pc = ((fq ^ sa) & 3) << 3;             // swizzled col offset

    for (int t = 0; t < NT; ++t) {
        // wait own loads for tile t; keep later tiles in flight
        if (t + 3 <= NT)      asm volatile("s_waitcnt vmcnt(8)" ::: "memory");
        else if (t + 2 == NT) asm volatile("s_waitcnt vmcnt(4)" ::: "memory");
        else                  asm volatile("s_waitcnt vmcnt(0)" ::: "memory");
        __builtin_amdgcn_s_barrier();    // all waves' tile-t loads resident;
                                         // all waves done reading buf (t-1)&3
        if (t + 3 < NT) stage((t + 3) & 3, (t + 3) << 5);

        const int base = (t & 3) << 14;
        bf16x8 a[8], b[4];
#pragma unroll
        for (int m = 0; m < 8; ++m)
            a[m] = *(const bf16x8*)&lds[base + (wm * 128 + m * 16 + fr) * 32 + pc];
#pragma unroll
        for (int n = 0; n < 4; ++n)
            b[n] = *(const bf16x8*)&lds[base + 8192 + (wn * 64 + n * 16 + fr) * 32 + pc];

        __builtin_amdgcn_s_setprio(1);
#pragma unroll
        for (int m = 0; m < 8; ++m)
#pragma unroll
            for (int n = 0; n < 4; ++n)
                acc[m][n] = __builtin_amdgcn_mfma_f32_16x16x32_bf16(
                    a[m], b[n], acc[m][n], 0, 0, 0);
        __builtin_amdgcn_s_setprio(0);
    }

    // epilogue: C/D layout col=lane&15, row=(lane>>4)*4+r ; bias + ReLU, bf16
#pragma unroll
    for (int m = 0; m < 8; ++m) {
        const size_t rowb = brow + wm * 128 + m * 16 + fq * 4;
#pragma unroll
        for (int n = 0; n < 4; ++n) {
            const int col = bcol + wn * 64 + n * 16 + fr;
            const float bv = bias[col];
#pragma unroll
            for (int r = 0; r < 4; ++r) {
                float v = fmaxf(acc[m][n][r] + bv, 0.f);
                C[(rowb + r) * (size_t)ldc + col] = f2bf(v);
            }
        }
    }
}

// ---------------------------------------------------------------------------
// 128x128 MFMA GEMM (verified round-2/3 kernel) for small-N dispatches.
// ---------------------------------------------------------------------------
template<bool OBF16, bool RELU>
__global__ __launch_bounds__(256)
void gemm_mfma(const ushort_t* __restrict__ A, int lda,
               const ushort_t* __restrict__ A2, int lda2, int ksplit,
               const ushort_t* __restrict__ Bt,
               const float* __restrict__ bias,
               void* __restrict__ C, int ldc, int N, int K, int lgx)
{
    __shared__ ushort_t As[2][128 * 64];
    __shared__ ushort_t Bs[2][128 * 64];

    const int tid  = threadIdx.x;
    const int w    = tid >> 6;
    const int lane = tid & 63;
    const int wm   = w >> 1;
    const int wn   = w & 1;

    const int bid  = blockIdx.x;
    const int xcd  = bid & 7;
    const int slot = bid >> 3;
    const int x    = slot & ((1 << lgx) - 1);
    const int y    = xcd * 128 + (slot >> lgx);
    const size_t brow = (size_t)y * 128;
    const int    bcol = x * 128;

    const int fr   = lane & 15;
    const int fq   = lane >> 4;
    const int srow = lane >> 3;
    const int scol = (lane & 7) << 3;

    f32x4 acc[4][4];
#pragma unroll
    for (int i = 0; i < 4; ++i)
#pragma unroll
        for (int j = 0; j < 4; ++j) acc[i][j] = (f32x4){0.f, 0.f, 0.f, 0.f};

    const int NT = K >> 6;

    auto stage = [&](int buf, int k0) {
#pragma unroll
        for (int i = 0; i < 4; ++i) {
            const int c = (w << 2) + i;
            const int r = (c << 3) + srow;
            const ushort_t* asrc;
            if (k0 >= ksplit)
                asrc = A2 + (brow + r) * (size_t)lda2 + (k0 - ksplit) + scol;
            else
                asrc = A  + (brow + r) * (size_t)lda  + k0 + scol;
            gload_lds16(asrc, &As[buf][(c << 9) + lane * 8]);
            gload_lds16(Bt + (size_t)(bcol + r) * K + k0 + scol,
                        &Bs[buf][(c << 9) + lane * 8]);
        }
    };

    stage(0, 0);
    __syncthreads();

    for (int t = 0; t < NT; ++t) {
        const int cur = t & 1;
        if (t + 1 < NT) stage(cur ^ 1, (t + 1) << 6);
#pragma unroll
        for (int kk = 0; kk < 2; ++kk) {
            bf16x8 a[4], b[4];
#pragma unroll
            for (int f = 0; f < 4; ++f) {
                a[f] = *(const bf16x8*)&As[cur][(wm * 64 + f * 16 + fr) * 64 + kk * 32 + fq * 8];
                b[f] = *(const bf16x8*)&Bs[cur][(wn * 64 + f * 16 + fr) * 64 + kk * 32 + fq * 8];
            }
#pragma unroll
            for (int fm = 0; fm < 4; ++fm)
#pragma unroll
                for (int fn = 0; fn < 4; ++fn)
                    acc[fm][fn] = __builtin_amdgcn_mfma_f32_16x16x32_bf16(
                        a[fm], b[fn], acc[fm][fn], 0, 0, 0);
        }
        __syncthreads();
    }

#pragma unroll
    for (int fm = 0; fm < 4; ++fm) {
        const size_t rowb = brow + wm * 64 + fm * 16 + fq * 4;
#pragma unroll
        for (int fn = 0; fn < 4; ++fn) {
            const int col = bcol + wn * 64 + fn * 16 + fr;
            if (col < N) {
                const float bv = bias[col];
#pragma unroll
                for (int r = 0; r < 4; ++r) {
                    float v = acc[fm][fn][r] + bv;
                    if (RELU) v = fmaxf(v, 0.f);
                    const size_t idx = (rowb + r) * (size_t)ldc + col;
                    if (OBF16) ((ushort_t*)C)[idx] = f2bf(v);
                    else       ((float*)C)[idx]    = v;
                }
            }
        }
    }
}

// ---------------------------------------------------------------------------
// weight transpose+convert: Wt[n][k] = bf16(W[k][n]), zero-pad n in [N,Npad)
// ---------------------------------------------------------------------------
__global__ __launch_bounds__(256)
void transpose_w(const float* __restrict__ W, ushort_t* __restrict__ Wt,
                 int K, int N, int Npad)
{
    int idx = blockIdx.x * 256 + threadIdx.x;
    if (idx >= Npad * K) return;
    int n = idx / K, k = idx - n * K;
    float v = (n < N) ? W[(size_t)k * N + n] : 0.f;
    Wt[idx] = f2bf(v);
}

__global__ __launch_bounds__(256)
void transpose_wk(const float* __restrict__ W, ushort_t* __restrict__ Wt,
                  int Ksrc, int N, int ldk, int kOff, float sign)
{
    int idx = blockIdx.x * 256 + threadIdx.x;
    if (idx >= N * Ksrc) return;
    int n = idx / Ksrc, k = idx - n * Ksrc;
    Wt[(size_t)n * ldk + kOff + k] = f2bf(sign * W[(size_t)k * N + n]);
}

__global__ __launch_bounds__(256)
void conv_f32_bf16(const float* __restrict__ src, ushort_t* __restrict__ dst)
{
    size_t q = (size_t)blockIdx.x * 256 + threadIdx.x;
    float4 v = ((const float4*)src)[q];
    ushort_t* d = dst + q * 4;
    d[0] = f2bf(v.x); d[1] = f2bf(v.y); d[2] = f2bf(v.z); d[3] = f2bf(v.w);
}

__global__ void pack_bias(const float* __restrict__ bk, const float* __restrict__ bq,
                          const float* __restrict__ bv, float* __restrict__ pb)
{
    int j = threadIdx.x;
    float v = 0.f;
    if      (j < 32)  v = bk[j];
    else if (j < 64)  v = bq[j - 32];
    else if (j < 192) v = bv[j - 64];
    pb[j] = v;
}

__global__ void make_cbias(const float* __restrict__ bt2, const float* __restrict__ bp3,
                           float* __restrict__ cb)
{
    int j = threadIdx.x;
    cb[j] = bt2[j] - bp3[j];
}

// ---------------------------------------------------------------------------
// int_imp[b,a] = softmax_a( mean_c diff[b,a,c]^2 ), diff bf16 [BB,AA,128]
// ---------------------------------------------------------------------------
__global__ __launch_bounds__(64)
void mse_softmax(const ushort_t* __restrict__ diff, float* __restrict__ int_imp)
{
    const int b = blockIdx.x, lane = threadIdx.x;
    __shared__ float m[AA];
    for (int a = 0; a < AA; ++a) {
        const uint32_t u = *(const uint32_t*)(diff + ((size_t)b * AA + a) * 128 + lane * 2);
        float d0 = bf2f((ushort_t)(u & 0xffff));
        float d1 = bf2f((ushort_t)(u >> 16));
        float s = d0 * d0 + d1 * d1;
#pragma unroll
        for (int off = 32; off > 0; off >>= 1) s += __shfl_down(s, off);
        if (lane == 0) m[a] = s * (1.f / 128.f);
    }
    __syncthreads();
    if (lane == 0) {
        float mx = -1e30f;
#pragma unroll
        for (int a = 0; a < AA; ++a) mx = fmaxf(mx, m[a]);
        float e[AA], den = 0.f;
#pragma unroll
        for (int a = 0; a < AA; ++a) { e[a] = __expf(m[a] - mx); den += e[a]; }
        float inv = 1.f / den;
#pragma unroll
        for (int a = 0; a < AA; ++a) int_imp[(size_t)b * AA + a] = e[a] * inv;
    }
}

// ---------------------------------------------------------------------------
// attention: kvq packed [BA][192] = [key(32)|qry(32)|val(128)] per row.
// ---------------------------------------------------------------------------
__global__ __launch_bounds__(256)
void attn_apply(const ushort_t* __restrict__ kvq, const float* __restrict__ Wa,
                const float* __restrict__ ba, const float* __restrict__ iimp,
                ushort_t* __restrict__ applied)
{
    const int b = blockIdx.x, t = threadIdx.x;
    __shared__ float klds[512], qlds[512];
    __shared__ ushort_t vlds[2048];
    __shared__ float part[16][17];
    __shared__ float kp[16];
    __shared__ float attn[16][17];

    for (int i = t; i < 512; i += 256) {
        int a = i >> 5, c = i & 31;
        const size_t base = ((size_t)b * AA + a) * 192;
        klds[i] = bf2f(kvq[base + c]);
        qlds[i] = bf2f(kvq[base + 32 + c]);
    }
    for (int i = t; i < 2048; i += 256) {
        int j = i >> 7, v = i & 127;
        vlds[i] = kvq[((size_t)b * AA + j) * 192 + 64 + v];
    }
    __syncthreads();

    {
        int j = t & 15, seg = t >> 4;
        float s = 0.f;
        for (int c = seg * 32; c < seg * 32 + 32; ++c)
            s += klds[c] * Wa[(32 + c) * 16 + j];
        part[j][seg] = s;
    }
    __syncthreads();
    if (t < 16) {
        float s = 0.f;
#pragma unroll
        for (int seg = 0; seg < 16; ++seg) s += part[t][seg];
        kp[t] = s;
    }
    __syncthreads();

    {
        int i = t >> 4, j = t & 15;
        float s = 0.f;
#pragma unroll
        for (int q = 0; q < 32; ++q) s += qlds[i * 32 + q] * Wa[q * 16 + j];
        attn[i][j] = s + kp[j] + ba[j];
    }
    __syncthreads();
    if (t < 16) {
        float mx = -1e30f;
#pragma unroll
        for (int j = 0; j < 16; ++j) mx = fmaxf(mx, attn[t][j]);
        float e[16], den = 0.f;
#pragma unroll
        for (int j = 0; j < 16; ++j) { e[j] = __expf(attn[t][j] - mx); den += e[j]; }
        float inv = 1.f / den;
#pragma unroll
        for (int j = 0; j < 16; ++j)
            attn[t][j] = e[j] * inv + 0.5f * iimp[b * 16 + j];
    }
    __syncthreads();

    for (int o = t; o < 2048; o += 256) {
        int i = o >> 7, v = o & 127;
        float s = 0.f;
#pragma unroll
        for (int j = 0; j < 16; ++j) s += attn[i][j] * bf2f(vlds[j * 128 + v]);
        applied[((size_t)b * AA + i) * 128 + v] = f2bf(s);
    }
}

// ---------------------------------------------------------------------------
// launch
// ---------------------------------------------------------------------------
extern "C" void kernel_launch(void* const* d_in, const int* in_sizes, int n_in,
                              void* d_out, int out_size, void* d_ws, size_t ws_size,
                              hipStream_t stream)
{
    const float* x      = (const float*)d_in[0];
    const float* hidden = (const float*)d_in[1];
    const float* Wk  = (const float*)d_in[2];
    const float* bk  = (const float*)d_in[3];
    const float* Wv  = (const float*)d_in[4];
    const float* bv  = (const float*)d_in[5];
    const float* Wq  = (const float*)d_in[6];
    const float* bq  = (const float*)d_in[7];
    const float* Wa  = (const float*)d_in[8];
    const float* ba  = (const float*)d_in[9];
    const float* Wt1 = (const float*)d_in[10];
    const float* bt1 = (const float*)d_in[11];
    const float* Wt2 = (const float*)d_in[12];
    const float* bt2 = (const float*)d_in[13];
    const float* Wp1 = (const float*)d_in[14];
    const float* bp1 = (const float*)d_in[15];
    const float* Wp2 = (const float*)d_in[16];
    const float* bp2 = (const float*)d_in[17];
    const float* Wp3 = (const float*)d_in[18];
    const float* bp3 = (const float*)d_in[19];
    const float* Wc  = (const float*)d_in[20];
    const float* bc  = (const float*)d_in[21];
    const float* W2  = (const float*)d_in[22];
    const float* b2  = (const float*)d_in[23];

    float*    out = (float*)d_out;
    ushort_t* ws  = (ushort_t*)d_ws;

    ushort_t* xb  = ws;                       // [BA*512]
    ushort_t* ht  = xb + (size_t)BA * 512;    // [BA*1024] = [h_t | h_p2]
    ushort_t* hp1 = ht + (size_t)BA * 1024;   // [BA*512]
    ushort_t* WT  = hp1 + (size_t)BA * 512;
    ushort_t* diff    = xb;                   // BA*128 (after xb dead)
    ushort_t* kvq     = xb + (size_t)BA * 128;// BA*192
    ushort_t* hiddenb = hp1;                  // BA*256 (after h_p1 dead)
    ushort_t* applied = ht;                   // BA*128 (after ht dead)
    ushort_t* comb    = ht + (size_t)BA * 512;// BA*256

    ushort_t* Wt1t = WT;                    // 512*512
    ushort_t* Wp1t = Wt1t + 512 * 512;
    ushort_t* Wp2t = Wp1t + 512 * 512;
    ushort_t* Dt   = Wp2t + 512 * 512;      // 128*1024
    ushort_t* Wkvq = Dt   + 128 * 1024;     // 256*256
    ushort_t* Wct  = Wkvq + 256 * 256;      // 256*384
    ushort_t* W2t  = Wct  + 256 * 384;      // 128*256
    float* pbias = (float*)(W2t + 128 * 256);
    float* cbias = pbias + 256;
    float* iimp  = cbias + 128;

    const dim3 blk(256);
    const int BIG = 1 << 30;

    conv_f32_bf16<<<65536, blk, 0, stream>>>(x, xb);
    transpose_w<<<1024, blk, 0, stream>>>(Wt1, Wt1t, 512, 512, 512);
    transpose_w<<<1024, blk, 0, stream>>>(Wp1, Wp1t, 512, 512, 512);
    transpose_w<<<1024, blk, 0, stream>>>(Wp2, Wp2t, 512, 512, 512);
    transpose_wk<<<256, blk, 0, stream>>>(Wt2, Dt, 512, 128, 1024, 0,    1.f);
    transpose_wk<<<256, blk, 0, stream>>>(Wp3, Dt, 512, 128, 1024, 512, -1.f);
    transpose_w<<<32,  blk, 0, stream>>>(Wk, Wkvq + 0 * 256,   256, 32, 32);
    transpose_w<<<32,  blk, 0, stream>>>(Wq, Wkvq + 32 * 256,  256, 32, 32);
    transpose_w<<<128, blk, 0, stream>>>(Wv, Wkvq + 64 * 256,  256, 128, 128);
    transpose_w<<<64,  blk, 0, stream>>>(Wk, Wkvq + 192 * 256, 256, 0, 64);
    transpose_w<<<384, blk, 0, stream>>>(Wc, Wct, 384, 256, 256);
    transpose_w<<<128, blk, 0, stream>>>(W2, W2t, 256, 64, 128);
    pack_bias<<<1, 256, 0, stream>>>(bk, bq, bv, pbias);
    make_cbias<<<1, 128, 0, stream>>>(bt2, bp3, cbias);

    // ---- phase 1: predictors (256^2 pipeline kernel) ---------------------
    gemm256<<<1024, 512, 0, stream>>>(xb, 512, xb, 512, BIG, Wt1t, bt1, ht,       1024, 512, 1, 64);
    gemm256<<<1024, 512, 0, stream>>>(xb, 512, xb, 512, BIG, Wp1t, bp1, hp1,       512, 512, 1, 64);
    gemm256<<<1024, 512, 0, stream>>>(hp1, 512, hp1, 512, BIG, Wp2t, bp2, ht + 512, 1024, 512, 1, 64);
    conv_f32_bf16<<<32768, blk, 0, stream>>>(hidden, hiddenb);
    gemm_mfma<true, false><<<1024, blk, 0, stream>>>(ht, 1024, ht, 1024, BIG, Dt, cbias, diff, 128, 128, 1024, 0);
    mse_softmax<<<BB, 64, 0, stream>>>(diff, iimp);

    // ---- phase 2: communicate -------------------------------------------
    gemm_mfma<true, false><<<2048, blk, 0, stream>>>(hiddenb, 256, hiddenb, 256, BIG, Wkvq, pbias, kvq, 192, 192, 256, 1);
    attn_apply<<<BB, blk, 0, stream>>>(kvq, Wa, ba, iimp, applied);

    // ---- phase 3: combine + head ----------------------------------------
    gemm256<<<512, 512, 0, stream>>>(applied, 128, hiddenb, 256, 128, Wct, bc, comb, 256, 384, 0, 64);
    gemm_mfma<false, false><<<1024, blk, 0, stream>>>(comb, 256, comb, 256, BIG, W2t, b2, out, 64, 64, 256, 0);
}